// Round 4
// baseline (571.862 us; speedup 1.0000x reference)
//
#include <hip/hip_runtime.h>
#include <cstdint>
#include <cstddef>

// Problem constants (from reference)
#define N_TOK 4096
#define K_DIM 4096
#define M_DIM 12288

using i32x4  = __attribute__((ext_vector_type(4)))  int;
using i32x16 = __attribute__((ext_vector_type(16))) int;

// ---------------- pack int32 -> int8 (fully coalesced) ----------------
constexpr long GROUPS_X     = (long)N_TOK * K_DIM / 4;               // 4,194,304
constexpr long GROUPS_TOTAL = ((long)N_TOK + M_DIM) * K_DIM / 4;     // 16,777,216

__global__ __launch_bounds__(256) void pack_i8_kernel(
    const int* __restrict__ x, const int* __restrict__ w, int* __restrict__ out8)
{
  const long stride = (long)gridDim.x * 256;
  for (long g = (long)blockIdx.x * 256 + threadIdx.x; g < GROUPS_TOTAL; g += stride) {
    const int* src = (g < GROUPS_X) ? (x + g * 4) : (w + (g - GROUPS_X) * 4);
    i32x4 v = *(const i32x4*)src;
    out8[g] = (v.x & 0xff) | ((v.y & 0xff) << 8) | ((v.z & 0xff) << 16) | (v.w << 24);
  }
}

// ---------------- i8 GEMM, 256x256, 32x32x32 MFMA, 8-phase pipeline ----------------
#define BM 256
#define BN 256
#define KT 32                        // K_DIM / 128 bytes per K-tile
#define GRID_M (N_TOK / BM)          // 16
#define GRID_N (M_DIM / BN)          // 48
#define NWG (GRID_M * GRID_N)        // 768

__device__ __forceinline__ void load_lds16(const void* g, void* l) {
  __builtin_amdgcn_global_load_lds(
      (const __attribute__((address_space(1))) void*)g,
      (__attribute__((address_space(3))) void*)l, 16, 0, 0);
}

// LDS map: region(buf, ab, s) = (buf*4 + ab*2 + s) * 16384 bytes.
// Region: [256 rows][64 B] row-major (64 B = 2 ksteps of K=32 i8).
// Swizzle (both-sides involution): 16-B slot' = slot ^ ((row >> 1) & 3).
// Frag reads (32x32): 64 lanes = 8 bank-spans x 8 lanes -> minimum 8 passes,
// zero structural conflict (same invariant as the measured-0 R3 layout).

// Stage one region = 2 global_load_lds per thread. g0 = per-thread source
// base (row/slot precomputed); chunk1 = +128 rows. BUF/AB/S compile-time.
template <int BUF, int S>
__device__ __forceinline__ void stage2(int8_t* lds, int ab, int ktarg,
                                       const int8_t* g0, int tid)
{
  const int lb = (BUF * 4 + ab * 2 + S) * 16384;
  const size_t ko = (size_t)ktarg * 128 + S * 64;      // wave-uniform
  load_lds16(g0 + ko, lds + lb + tid * 16);
  load_lds16(g0 + (size_t)128 * K_DIM + ko, lds + lb + 8192 + tid * 16);
}

#define MFMA8(ACCROW)                                                          \
  acc[0][0] = __builtin_amdgcn_mfma_i32_32x32x32_i8(a0, b0, acc[0][0], 0, 0, 0); \
  acc[0][1] = __builtin_amdgcn_mfma_i32_32x32x32_i8(a0, b1, acc[0][1], 0, 0, 0); \
  acc[1][0] = __builtin_amdgcn_mfma_i32_32x32x32_i8(a1, b0, acc[1][0], 0, 0, 0); \
  acc[1][1] = __builtin_amdgcn_mfma_i32_32x32x32_i8(a1, b1, acc[1][1], 0, 0, 0); \
  acc[2][0] = __builtin_amdgcn_mfma_i32_32x32x32_i8(a2, b0, acc[2][0], 0, 0, 0); \
  acc[2][1] = __builtin_amdgcn_mfma_i32_32x32x32_i8(a2, b1, acc[2][1], 0, 0, 0); \
  acc[3][0] = __builtin_amdgcn_mfma_i32_32x32x32_i8(a3, b0, acc[3][0], 0, 0, 0); \
  acc[3][1] = __builtin_amdgcn_mfma_i32_32x32x32_i8(a3, b1, acc[3][1], 0, 0, 0);

// One K-tile = 4 phases (one kstep of K=32 each). CUR compile-time (kt-loop
// unrolled x2) -> all LDS bases are constants, ds_reads fold to base+imm.
// MODE: 2 = steady (stage kt+1.s1 in p0/p1, kt+2.s0 in p2/p3, vmcnt(4)),
// 1 = kt==30 (stage kt+1.s1 only, vmcnt(0)), 0 = last tile (nothing).
template <int MODE, int CUR>
__device__ __forceinline__ void ktile(
    int kt, int8_t* lds, const int8_t* gA, const int8_t* gB, int tid,
    int aoff0, int aoff1, int boff0, int boff1, i32x16 (&acc)[4][2])
{
  constexpr int aB0 = (CUR * 4 + 0) * 16384;   // A s=0
  constexpr int aB1 = (CUR * 4 + 1) * 16384;   // A s=1
  constexpr int bB0 = (CUR * 4 + 2) * 16384;   // B s=0
  constexpr int bB1 = (CUR * 4 + 3) * 16384;   // B s=1

  // ---- p0: s=0, ks=0 ----
  {
    i32x4 b0 = *(const i32x4*)&lds[bB0 + boff0];
    i32x4 b1 = *(const i32x4*)&lds[bB0 + boff0 + 2048];
    i32x4 a0 = *(const i32x4*)&lds[aB0 + aoff0];
    i32x4 a1 = *(const i32x4*)&lds[aB0 + aoff0 + 2048];
    i32x4 a2 = *(const i32x4*)&lds[aB0 + aoff0 + 4096];
    i32x4 a3 = *(const i32x4*)&lds[aB0 + aoff0 + 6144];
    if (MODE >= 1) stage2<(CUR ^ 1), 1>(lds, 0, kt + 1, gA, tid);
    __builtin_amdgcn_s_barrier();
    __builtin_amdgcn_s_setprio(1);
    MFMA8(0)
    __builtin_amdgcn_s_setprio(0);
    __builtin_amdgcn_s_barrier();
  }
  // ---- p1: s=0, ks=1 ----
  {
    i32x4 b0 = *(const i32x4*)&lds[bB0 + boff1];
    i32x4 b1 = *(const i32x4*)&lds[bB0 + boff1 + 2048];
    i32x4 a0 = *(const i32x4*)&lds[aB0 + aoff1];
    i32x4 a1 = *(const i32x4*)&lds[aB0 + aoff1 + 2048];
    i32x4 a2 = *(const i32x4*)&lds[aB0 + aoff1 + 4096];
    i32x4 a3 = *(const i32x4*)&lds[aB0 + aoff1 + 6144];
    if (MODE >= 1) stage2<(CUR ^ 1), 1>(lds, 1, kt + 1, gB, tid);
    __builtin_amdgcn_s_barrier();
    __builtin_amdgcn_s_setprio(1);
    MFMA8(0)
    __builtin_amdgcn_s_setprio(0);
    __builtin_amdgcn_s_barrier();
  }
  // ---- p2: s=1, ks=0 (overwrite of (CUR,*,0) is safe: its last reads were
  // drained before p1's MFMA, and p1 ended with a barrier) ----
  {
    i32x4 b0 = *(const i32x4*)&lds[bB1 + boff0];
    i32x4 b1 = *(const i32x4*)&lds[bB1 + boff0 + 2048];
    i32x4 a0 = *(const i32x4*)&lds[aB1 + aoff0];
    i32x4 a1 = *(const i32x4*)&lds[aB1 + aoff0 + 2048];
    i32x4 a2 = *(const i32x4*)&lds[aB1 + aoff0 + 4096];
    i32x4 a3 = *(const i32x4*)&lds[aB1 + aoff0 + 6144];
    if (MODE == 2) stage2<CUR, 0>(lds, 0, kt + 2, gA, tid);
    __builtin_amdgcn_s_barrier();
    __builtin_amdgcn_s_setprio(1);
    MFMA8(0)
    __builtin_amdgcn_s_setprio(0);
    __builtin_amdgcn_s_barrier();
  }
  // ---- p3: s=1, ks=1; K-tile checkpoint ----
  {
    i32x4 b0 = *(const i32x4*)&lds[bB1 + boff1];
    i32x4 b1 = *(const i32x4*)&lds[bB1 + boff1 + 2048];
    i32x4 a0 = *(const i32x4*)&lds[aB1 + aoff1];
    i32x4 a1 = *(const i32x4*)&lds[aB1 + aoff1 + 2048];
    i32x4 a2 = *(const i32x4*)&lds[aB1 + aoff1 + 4096];
    i32x4 a3 = *(const i32x4*)&lds[aB1 + aoff1 + 6144];
    if (MODE == 2) stage2<CUR, 0>(lds, 1, kt + 2, gB, tid);
    __builtin_amdgcn_s_barrier();
    __builtin_amdgcn_s_setprio(1);
    MFMA8(0)
    __builtin_amdgcn_s_setprio(0);
    // Counted checkpoint: drains kt+1 (both s), leaves kt+2.s0 in flight.
    if (MODE == 2)      asm volatile("s_waitcnt vmcnt(4)" ::: "memory");
    else if (MODE == 1) asm volatile("s_waitcnt vmcnt(0)" ::: "memory");
    __builtin_amdgcn_s_barrier();
  }
}

__global__ __launch_bounds__(512, 2) void w8a8_gemm_kernel(
    const int8_t* __restrict__ A8,            // [N_TOK][K_DIM]
    const int8_t* __restrict__ B8,            // [M_DIM][K_DIM]
    const float* __restrict__ input_scale,    // [N_TOK]
    const float* __restrict__ dequant_scale,  // [M_DIM]
    const float* __restrict__ bias,           // [M_DIM]
    float* __restrict__ out)                  // [N_TOK][M_DIM] f32
{
  __shared__ int8_t lds[131072];              // 128 KiB -> 1 block/CU

  const int tid  = threadIdx.x;
  const int lane = tid & 63;
  const int wid  = tid >> 6;      // 0..7 (2M x 4N waves)
  const int wr   = wid >> 2;      // 0..1 -> 128-row half
  const int wc   = wid & 3;       // 0..3 -> 64-col slice
  const int l31  = lane & 31;
  const int lh   = lane >> 5;
  const int xsw  = (l31 >> 1) & 3;            // row-derived swizzle XOR

  // Loop-invariant fragment read bases (s/ks region offsets are imm).
  const int aoff0 = (wr * 128 + l31) * 64 + ((0 + lh) ^ xsw) * 16;  // ks=0
  const int aoff1 = (wr * 128 + l31) * 64 + ((2 + lh) ^ xsw) * 16;  // ks=1
  const int boff0 = (wc * 64 + l31) * 64 + ((0 + lh) ^ xsw) * 16;
  const int boff1 = (wc * 64 + l31) * 64 + ((2 + lh) ^ xsw) * 16;

  // XCD-aware swizzle (768 % 8 == 0 -> bijective) + GROUP_M=4 chunking
  int bid = blockIdx.x;
  int w_  = (bid & 7) * (NWG / 8) + (bid >> 3);
  const int width = 4 * GRID_N;   // 192
  int gid = w_ / width, rem = w_ % width;
  int bm = gid * 4 + (rem & 3);
  int bn = rem >> 2;
  const int brow = bm * BM;
  const int bcol = bn * BN;

  // Per-thread global stage bases (chunk0: row=tid>>2, inverse-swizzled slot)
  const int srow  = tid >> 2;
  const int sslot = (tid & 3) ^ ((srow >> 1) & 3);
  const int8_t* gA = A8 + (size_t)(brow + srow) * K_DIM + sslot * 16;
  const int8_t* gB = B8 + (size_t)(bcol + srow) * K_DIM + sslot * 16;

  i32x16 acc[4][2] = {};

  // Prologue: tile0 (4 regions) + tile1.s0 (2 regions) = 12 loads.
  stage2<0, 0>(lds, 0, 0, gA, tid);
  stage2<0, 0>(lds, 1, 0, gB, tid);
  stage2<0, 1>(lds, 0, 0, gA, tid);
  stage2<0, 1>(lds, 1, 0, gB, tid);
  stage2<1, 0>(lds, 0, 1, gA, tid);
  stage2<1, 0>(lds, 1, 1, gB, tid);
  asm volatile("s_waitcnt vmcnt(4)" ::: "memory");   // tile0 resident
  __builtin_amdgcn_s_barrier();

  for (int kt = 0; kt < KT - 2; kt += 2) {
    ktile<2, 0>(kt,     lds, gA, gB, tid, aoff0, aoff1, boff0, boff1, acc);
    ktile<2, 1>(kt + 1, lds, gA, gB, tid, aoff0, aoff1, boff0, boff1, acc);
  }
  ktile<1, 0>(KT - 2, lds, gA, gB, tid, aoff0, aoff1, boff0, boff1, acc);
  ktile<0, 1>(KT - 1, lds, gA, gB, tid, aoff0, aoff1, boff0, boff1, acc);

  // Epilogue. C/D 32x32 layout: col = lane&31, row = (r&3)+8*(r>>2)+4*(lane>>5)
  const int orow = brow + wr * 128;
  const int ocol = bcol + wc * 64 + l31;
  const float dsc0 = dequant_scale[ocol];
  const float dsc1 = dequant_scale[ocol + 32];
  const float bs0  = bias[ocol];
  const float bs1  = bias[ocol + 32];
#pragma unroll
  for (int fi = 0; fi < 4; ++fi) {
#pragma unroll
    for (int r = 0; r < 16; ++r) {
      const int n = orow + fi * 32 + (r & 3) + 8 * (r >> 2) + 4 * lh;
      const float sv = input_scale[n];
      float* o = out + (size_t)n * M_DIM + ocol;
      o[0]  = (float)acc[fi][0][r] * sv * dsc0 + bs0;
      o[32] = (float)acc[fi][1][r] * sv * dsc1 + bs1;
    }
  }
}

extern "C" void kernel_launch(void* const* d_in, const int* in_sizes, int n_in,
                              void* d_out, int out_size, void* d_ws, size_t ws_size,
                              hipStream_t stream) {
  const int*   x             = (const int*)d_in[0];     // [N,K] int32 (values fit i8)
  const int*   w             = (const int*)d_in[1];     // [M,K] int32
  const float* input_scale   = (const float*)d_in[2];   // [N]
  const float* dequant_scale = (const float*)d_in[3];   // [M]
  const float* bias          = (const float*)d_in[4];   // [M]
  float*       out           = (float*)d_out;           // [N,M] f32

  int8_t* x8 = (int8_t*)d_ws;                           // 16 MB
  int8_t* w8 = x8 + (size_t)N_TOK * K_DIM;              // 48 MB, contiguous

  pack_i8_kernel<<<4096, 256, 0, stream>>>(x, w, (int*)d_ws);
  w8a8_gemm_kernel<<<NWG, 512, 0, stream>>>(x8, w8, input_scale, dequant_scale,
                                            bias, out);
}